// Round 1
// baseline (1599.857 us; speedup 1.0000x reference)
//
#include <hip/hip_runtime.h>

#define NB 256   // batch
#define NF 64    // fields
#define NE 64    // embedding dim (== wave size)
#define NO 128   // filters per layer

// One CIN layer for one batch sample, computed by the whole block.
// xk_new[o,e] = relu( sum_{f,c} W[o, f*C + c] * x0[f,e] * xk[c,e] )
// Each wave owns 8 consecutive o's; lane == e.
template <int C>
__device__ __forceinline__ void cin_layer(
    const float* __restrict__ Wl,          // (NO, NF*C)
    const float (*__restrict__ xks)[NE],   // (C, NE) in LDS
    const float (*__restrict__ x0s)[NE],   // (NF, NE) in LDS
    float (*__restrict__ xns)[NE],         // (NO, NE) out in LDS
    const float* __restrict__ Wa_l,        // Wa + layer*NO
    float& ypart, int wave_u, int lane, bool write_out)
{
    const int o0 = wave_u * 8;
    float acc[8];
#pragma unroll
    for (int j = 0; j < 8; ++j) acc[j] = 0.f;

    for (int f = 0; f < NF; ++f) {
        const float x0v = x0s[f][lane];
        float t[8];
#pragma unroll
        for (int j = 0; j < 8; ++j) t[j] = 0.f;
        // Row base for this (o-block, f); wave-uniform -> scalar (s_load) path.
        const float* __restrict__ wbase = Wl + (size_t)o0 * (NF * C) + (size_t)f * C;
#pragma unroll 8
        for (int c = 0; c < C; ++c) {
            const float xv = xks[c][lane];   // conflict-free LDS read
#pragma unroll
            for (int j = 0; j < 8; ++j)
                t[j] = fmaf(wbase[(size_t)j * (NF * C) + c], xv, t[j]);
        }
#pragma unroll
        for (int j = 0; j < 8; ++j) acc[j] = fmaf(x0v, t[j], acc[j]);
    }

#pragma unroll
    for (int j = 0; j < 8; ++j) {
        const float v = fmaxf(acc[j], 0.f);
        if (write_out) xns[o0 + j][lane] = v;
        // y contribution: Wa[l,o] * sum_e v[o,e]; lane holds one e.
        ypart = fmaf(Wa_l[o0 + j], v, ypart);
    }
}

__global__ __launch_bounds__(1024) void cin_kernel(
    const float* __restrict__ x,    // (B, F, E)
    const float* __restrict__ W0,   // (NO, NF*NF)
    const float* __restrict__ W1,   // (NO, NF*NO)
    const float* __restrict__ W2,   // (NO, NF*NO)
    const float* __restrict__ Wa,   // (1, 3*NO)
    float* __restrict__ y)          // (B,)
{
    __shared__ float x0s[NF][NE];    // 16 KB
    __shared__ float bufA[NO][NE];   // 32 KB
    __shared__ float bufB[NO][NE];   // 32 KB
    __shared__ float ysum[16];

    const int b = blockIdx.x;
    const int tid = threadIdx.x;
    const int lane = tid & 63;
    const int wave_u = __builtin_amdgcn_readfirstlane(tid >> 6);

    // Stage x[b] into LDS: 4096 floats, 1024 threads x 4, coalesced.
    const float* __restrict__ xb = x + (size_t)b * NF * NE;
#pragma unroll
    for (int i = 0; i < 4; ++i) {
        const int idx = tid + i * 1024;
        ((float*)x0s)[idx] = xb[idx];
    }
    __syncthreads();

    float ypart = 0.f;
    // Layer 0: xk = x0 (C = NF)
    cin_layer<NF>(W0, x0s, x0s, bufA, Wa + 0 * NO, ypart, wave_u, lane, true);
    __syncthreads();
    // Layer 1 (C = NO)
    cin_layer<NO>(W1, bufA, x0s, bufB, Wa + 1 * NO, ypart, wave_u, lane, true);
    __syncthreads();
    // Layer 2 (C = NO); output only feeds the pooled sum -> skip LDS write.
    cin_layer<NO>(W2, bufB, x0s, bufA, Wa + 2 * NO, ypart, wave_u, lane, false);

    // Block-reduce ypart (1024 threads) -> y[b].
#pragma unroll
    for (int off = 32; off >= 1; off >>= 1)
        ypart += __shfl_down(ypart, off, 64);
    if (lane == 0) ysum[wave_u] = ypart;
    __syncthreads();
    if (tid == 0) {
        float s = 0.f;
#pragma unroll
        for (int w = 0; w < 16; ++w) s += ysum[w];
        y[b] = s;
    }
}

extern "C" void kernel_launch(void* const* d_in, const int* in_sizes, int n_in,
                              void* d_out, int out_size, void* d_ws, size_t ws_size,
                              hipStream_t stream) {
    const float* x  = (const float*)d_in[0];
    const float* W0 = (const float*)d_in[1];
    const float* W1 = (const float*)d_in[2];
    const float* W2 = (const float*)d_in[3];
    const float* Wa = (const float*)d_in[4];
    float* y = (float*)d_out;
    hipLaunchKernelGGL(cin_kernel, dim3(NB), dim3(1024), 0, stream,
                       x, W0, W1, W2, Wa, y);
}

// Round 2
// 181.700 us; speedup vs baseline: 8.8050x; 8.8050x over previous
//
#include <hip/hip_runtime.h>

#define NBATCH 256
#define NFIELD 64
#define NEMB   64
#define NFILT  128

typedef __attribute__((ext_vector_type(8))) short bf16x8;
typedef __attribute__((ext_vector_type(4))) float f32x4;

__device__ __forceinline__ unsigned short f2b(float f) {
    unsigned u = __float_as_uint(f);
    u = (u + 0x7fffu + ((u >> 16) & 1u)) >> 16;
    return (unsigned short)u;
}
__device__ __forceinline__ float b2f(unsigned short h) {
    return __uint_as_float(((unsigned)h) << 16);
}
__device__ __forceinline__ void async16(const void* g, void* l) {
    __builtin_amdgcn_global_load_lds((const __attribute__((address_space(1))) unsigned int*)g,
                                     (__attribute__((address_space(3))) unsigned int*)l, 16, 0, 0);
}

// ---------------- prep kernels ----------------
// W (NFILT x KDIM) fp32 -> bf16, tiled as [kstep][kseg(4)][row(128)][k8(8)]
// so one 8KB chunk stages linearly and A-frag ds_read_b128 granules spread mod-8.
__global__ void prep_w(const float* __restrict__ W, unsigned short* __restrict__ Wp, int KDIM) {
    int idx = blockIdx.x * 256 + threadIdx.x;
    if (idx >= NFILT * KDIM) return;
    int o = idx / KDIM, k = idx - o * KDIM;
    int kstep = k >> 5, kseg = (k >> 3) & 3, k8 = k & 7;
    Wp[kstep * 4096 + kseg * 1024 + o * 8 + k8] = f2b(W[idx]);
}

// x (B,F,E) fp32 -> x0f[b][f][e] bf16 (linear) and x0t[b][e][c=f] bf16
// with XOR-swizzled granules: byte = e*128 + (((f>>3)^(e&7))<<4) + (f&7)*2
__global__ void prep_x(const float* __restrict__ x, unsigned short* __restrict__ x0t,
                       unsigned short* __restrict__ x0f) {
    int idx = blockIdx.x * 256 + threadIdx.x;
    if (idx >= NBATCH * NFIELD * NEMB) return;
    int b = idx >> 12;
    int r = idx & 4095;
    int f = r >> 6, e = r & 63;
    unsigned short v = f2b(x[idx]);
    x0f[b * 4096 + f * 64 + e] = v;
    x0t[b * 4096 + e * 64 + ((((f >> 3) ^ (e & 7)) << 3) | (f & 7))] = v;
}

// ---------------- main fused kernel ----------------
#define WT_OFF   0        // 4 chunks x 2 buf x 8KB = 64 KB  (W tiles)
#define HT_OFF   65536    // 4 chunks x 2 buf x 4KB = 32 KB  (h tiles)
#define XK_OFF   98304    // 16 KB  xk (e-major, swizzled, rows of 256B)
#define X0T_OFF  114688   // 8 KB   x0 transposed (rows of 128B, swizzled)
#define X0F_OFF  122880   // 8 KB   x0 [f][e] linear
#define YS_OFF   131072
#define SMEM_SZ  131136

template<int KL, int CL, bool FIRST, bool LAST>
__device__ __forceinline__ void do_layer(char* sm,
                                         const unsigned short* __restrict__ Wp,
                                         const float* __restrict__ Wa_l,
                                         float& ypart, int tid)
{
    constexpr int NITER = KL / 128;          // 4 chunks of K=32 per iteration
    const int lane = tid & 63;
    const int w = tid >> 6;
    const int kg = w & 3, mh = w >> 2;       // 4 k-groups x 2 M-halves
    const int kseg = lane >> 4, l15 = lane & 15;
    // h-formation roles: 4 chunk-groups x (2 k-halves x 64 e)
    const int kgf = tid >> 7;
    const int ef  = tid & 63;
    const int khalf = (tid >> 6) & 1;
    constexpr int ROWB = FIRST ? 128 : 256;
    const char* XKb = sm + (FIRST ? X0T_OFF : XK_OFF);
    const unsigned short* X0F = (const unsigned short*)(sm + X0F_OFF);

    f32x4 acc[4][4];
#pragma unroll
    for (int i = 0; i < 4; ++i)
#pragma unroll
        for (int j = 0; j < 4; ++j) acc[i][j] = f32x4{0.f, 0.f, 0.f, 0.f};

    auto stage_W = [&](int buf, int it) {
        const char* src = (const char*)Wp + (size_t)it * 32768 + w * 4096 + lane * 16;
#pragma unroll
        for (int j = 0; j < 4; ++j)
            async16(src + j * 1024, sm + WT_OFF + buf * 32768 + w * 4096 + j * 1024);
    };

    auto form_H = [&](int buf, int it) {
        const int kstep = it * 4 + kgf;
        const int f = (kstep * 32) / CL;                 // field uniform per chunk
        const int cbase = (kstep * 32) % CL + khalf * 16;
        const float x0v = b2f(X0F[f * 64 + ef]);
        char* hdst = sm + HT_OFF + buf * 16384 + kgf * 4096 + khalf * 2048 + ef * 16;
#pragma unroll
        for (int h2 = 0; h2 < 2; ++h2) {
            const int c0 = cbase + h2 * 8;
            const uint4 kv = *(const uint4*)(XKb + ef * ROWB + (((c0 >> 3) ^ (ef & 7)) << 4));
            unsigned out[4];
            const unsigned kvw[4] = {kv.x, kv.y, kv.z, kv.w};
#pragma unroll
            for (int p = 0; p < 4; ++p) {
                float lo = x0v * b2f((unsigned short)(kvw[p] & 0xffffu));
                float hi = x0v * b2f((unsigned short)(kvw[p] >> 16));
                out[p] = (unsigned)f2b(lo) | ((unsigned)f2b(hi) << 16);
            }
            *(uint4*)(hdst + h2 * 1024) = make_uint4(out[0], out[1], out[2], out[3]);
        }
    };

    auto compute = [&](int buf) {
        const char* wt = sm + WT_OFF + buf * 32768 + kg * 8192 + kseg * 2048 + (mh * 64 + l15) * 16;
        const char* ht = sm + HT_OFF + buf * 16384 + kg * 4096 + kseg * 1024 + l15 * 16;
        bf16x8 a[4], bb[4];
#pragma unroll
        for (int mt = 0; mt < 4; ++mt) a[mt] = *(const bf16x8*)(wt + mt * 256);
#pragma unroll
        for (int nt = 0; nt < 4; ++nt) bb[nt] = *(const bf16x8*)(ht + nt * 256);
#pragma unroll
        for (int mt = 0; mt < 4; ++mt)
#pragma unroll
            for (int nt = 0; nt < 4; ++nt)
                acc[mt][nt] = __builtin_amdgcn_mfma_f32_16x16x32_bf16(a[mt], bb[nt], acc[mt][nt], 0, 0, 0);
    };

    stage_W(0, 0);
    form_H(0, 0);
    __syncthreads();
    for (int i = 0; i < NITER; ++i) {
        const int cur = i & 1;
        if (i + 1 < NITER) { stage_W(cur ^ 1, i + 1); form_H(cur ^ 1, i + 1); }
        compute(cur);
        __syncthreads();
    }

    // cross-k-group reduction: kg!=0 waves dump partials into WT/HT area (96 KB)
    f32x4* RED = (f32x4*)sm;
    if (kg != 0) {
        const int slot = mh * 3 + (kg - 1);
#pragma unroll
        for (int mt = 0; mt < 4; ++mt)
#pragma unroll
            for (int nt = 0; nt < 4; ++nt)
                RED[slot * 1024 + (mt * 4 + nt) * 64 + lane] = acc[mt][nt];
    }
    __syncthreads();
    if (kg == 0) {
#pragma unroll
        for (int s = 0; s < 3; ++s) {
            const int slot = mh * 3 + s;
#pragma unroll
            for (int mt = 0; mt < 4; ++mt)
#pragma unroll
                for (int nt = 0; nt < 4; ++nt)
                    acc[mt][nt] += RED[slot * 1024 + (mt * 4 + nt) * 64 + lane];
        }
        const int o0 = mh * 64 + (lane >> 4) * 4;
#pragma unroll
        for (int mt = 0; mt < 4; ++mt) {
            const int om = o0 + mt * 16;
            const float4 wa = *(const float4*)(Wa_l + om);
#pragma unroll
            for (int nt = 0; nt < 4; ++nt) {
                f32x4 v = acc[mt][nt];
                v.x = fmaxf(v.x, 0.f); v.y = fmaxf(v.y, 0.f);
                v.z = fmaxf(v.z, 0.f); v.w = fmaxf(v.w, 0.f);
                if (!LAST) {
                    const int e = nt * 16 + l15;
                    unsigned lo = (unsigned)f2b(v.x) | ((unsigned)f2b(v.y) << 16);
                    unsigned hi = (unsigned)f2b(v.z) | ((unsigned)f2b(v.w) << 16);
                    char* dst = sm + XK_OFF + e * 256 + (((om >> 3) ^ (e & 7)) << 4) + (om & 7) * 2;
                    *(uint2*)dst = make_uint2(lo, hi);
                }
                ypart = fmaf(wa.x, v.x, ypart);
                ypart = fmaf(wa.y, v.y, ypart);
                ypart = fmaf(wa.z, v.z, ypart);
                ypart = fmaf(wa.w, v.w, ypart);
            }
        }
    }
    __syncthreads();
}

__global__ __launch_bounds__(512, 2) void cin_main(
    const unsigned short* __restrict__ Wp0,
    const unsigned short* __restrict__ Wp1,
    const unsigned short* __restrict__ Wp2,
    const unsigned short* __restrict__ x0t,
    const unsigned short* __restrict__ x0f,
    const float* __restrict__ Wa,
    float* __restrict__ y)
{
    extern __shared__ char smem[];
    const int b = blockIdx.x;
    const int tid = threadIdx.x;
    const int lane = tid & 63;
    const int w = tid >> 6;

    // stage x0t / x0f (8 KB each) via DMA
    async16((const char*)x0t + b * 8192 + w * 1024 + lane * 16, smem + X0T_OFF + w * 1024);
    async16((const char*)x0f + b * 8192 + w * 1024 + lane * 16, smem + X0F_OFF + w * 1024);
    __syncthreads();

    float ypart = 0.f;
    do_layer<4096,  64, true,  false>(smem, Wp0, Wa + 0,   ypart, tid);
    do_layer<8192, 128, false, false>(smem, Wp1, Wa + 128, ypart, tid);
    do_layer<8192, 128, false, true >(smem, Wp2, Wa + 256, ypart, tid);

#pragma unroll
    for (int off = 32; off >= 1; off >>= 1)
        ypart += __shfl_down(ypart, off, 64);
    float* YS = (float*)(smem + YS_OFF);
    if (lane == 0 && (w & 3) == 0) YS[w >> 2] = ypart;
    __syncthreads();
    if (tid == 0) y[b] = YS[0] + YS[1];
}

extern "C" void kernel_launch(void* const* d_in, const int* in_sizes, int n_in,
                              void* d_out, int out_size, void* d_ws, size_t ws_size,
                              hipStream_t stream) {
    const float* x  = (const float*)d_in[0];
    const float* W0 = (const float*)d_in[1];
    const float* W1 = (const float*)d_in[2];
    const float* W2 = (const float*)d_in[3];
    const float* Wa = (const float*)d_in[4];
    float* y = (float*)d_out;

    char* ws = (char*)d_ws;
    unsigned short* Wp0 = (unsigned short*)(ws);                 // 1 MB
    unsigned short* Wp1 = (unsigned short*)(ws + (1u << 20));    // 2 MB
    unsigned short* Wp2 = (unsigned short*)(ws + (3u << 20));    // 2 MB
    unsigned short* x0t = (unsigned short*)(ws + (5u << 20));    // 2 MB
    unsigned short* x0f = (unsigned short*)(ws + (7u << 20));    // 2 MB

    hipLaunchKernelGGL(prep_w, dim3((NFILT * 4096 + 255) / 256), dim3(256), 0, stream, W0, Wp0, 4096);
    hipLaunchKernelGGL(prep_w, dim3((NFILT * 8192 + 255) / 256), dim3(256), 0, stream, W1, Wp1, 8192);
    hipLaunchKernelGGL(prep_w, dim3((NFILT * 8192 + 255) / 256), dim3(256), 0, stream, W2, Wp2, 8192);
    hipLaunchKernelGGL(prep_x, dim3((NBATCH * 4096 + 255) / 256), dim3(256), 0, stream, x, x0t, x0f);

    hipFuncSetAttribute((const void*)cin_main, hipFuncAttributeMaxDynamicSharedMemorySize, SMEM_SZ);
    hipLaunchKernelGGL(cin_main, dim3(NBATCH), dim3(512), SMEM_SZ, stream,
                       Wp0, Wp1, Wp2, x0t, x0f, Wa, y);
}

// Round 3
// 106.863 us; speedup vs baseline: 14.9711x; 1.7003x over previous
//
#include <hip/hip_runtime.h>

#define NBATCH 256
#define NFILT  128

typedef __attribute__((ext_vector_type(8))) short bf16x8;
typedef __attribute__((ext_vector_type(4))) float f32x4;

__device__ __forceinline__ unsigned short f2b(float f) {
    unsigned u = __float_as_uint(f);
    u = (u + 0x7fffu + ((u >> 16) & 1u)) >> 16;
    return (unsigned short)u;
}
__device__ __forceinline__ float b2f(unsigned short h) {
    return __uint_as_float(((unsigned)h) << 16);
}
__device__ __forceinline__ void async16(const void* g, void* l) {
    __builtin_amdgcn_global_load_lds((const __attribute__((address_space(1))) unsigned int*)g,
                                     (__attribute__((address_space(3))) unsigned int*)l, 16, 0, 0);
}

// ---- LDS map (dynamic) ----
#define XKA_OFF 0        // 16 KB  xk layer0->1  [e][c=o] swizzled, ROWB 256
#define XKB_OFF 16384    // 16 KB  xk layer1->2
#define X0T_OFF 32768    // 8 KB   x0 transposed [e][c=f] swizzled, ROWB 128
#define RED_OFF 40960    // 96 KB  6 slots x 16KB cross-kg reduction
#define YS_OFF  139264
#define SMEM_SZ 139328

// ---------------- prep kernels ----------------
// W (128 x K), k = f*C + c  ->  A-granule tiling:
// dst elem = (((((kg*16+fl)*ncs + cs)*2 + mh)*4 + mt)*64 + kseg*16 + l15)*8 + j
__global__ void prep_w(const float* __restrict__ W, unsigned short* __restrict__ Wp,
                       int CLOG, int KLOG) {
    int idx = blockIdx.x * 256 + threadIdx.x;
    int o = idx >> KLOG;
    int k = idx & ((1 << KLOG) - 1);
    int f = k >> CLOG, c = k & ((1 << CLOG) - 1);
    int kg = f >> 4, fl = f & 15;
    int cs = c >> 5, kseg = (c >> 3) & 3, j = c & 7;
    int mh = o >> 6, mt = (o >> 4) & 3, l15 = o & 15;
    int ncs = 1 << (CLOG - 5);
    size_t dst = ((((size_t)((kg * 16 + fl) * ncs + cs) * 2 + mh) * 4 + mt) * 64
                  + kseg * 16 + l15) * 8 + j;
    Wp[dst] = f2b(W[idx]);
}

// x (B,F,E) -> x0t[b][e][c=f] bf16, granule-swizzled: elem off = e*64 + ((f>>3 ^ (e&7))<<3 | (f&7))
__global__ void prep_x(const float* __restrict__ x, unsigned short* __restrict__ x0t) {
    int idx = blockIdx.x * 256 + threadIdx.x;
    int b = idx >> 12, r = idx & 4095, f = r >> 6, e = r & 63;
    x0t[b * 4096 + e * 64 + ((((f >> 3) ^ (e & 7)) << 3) | (f & 7))] = f2b(x[idx]);
}

// ---------------- main kernel ----------------
template<int NCS, int ROWB, bool LAST>
__device__ __forceinline__ void do_layer(
    const char* __restrict__ Ag,       // per-wave A stream base (global, pre-tiled bf16)
    const char* __restrict__ XKsrc,    // LDS B source [e][c] swizzled
    char* __restrict__ XKdst,          // LDS xk-next (ROWB 256)
    const char* __restrict__ X0T,      // LDS x0t (for per-f scales)
    char* __restrict__ RED,
    const float* __restrict__ Wa_l,
    float& ypart, int lane, int l15, int kseg, int e7, int mh, int kg)
{
    const f32x4 ZERO = {0.f, 0.f, 0.f, 0.f};
    f32x4 acc[4][4];
#pragma unroll
    for (int mt = 0; mt < 4; ++mt)
#pragma unroll
        for (int nt = 0; nt < 4; ++nt) acc[mt][nt] = ZERO;
    f32x4 accf[4][4];
    bf16x8 a0[4], a1[4], b0[4], b1[4];
    const char* bbase[4];
#pragma unroll
    for (int nt = 0; nt < 4; ++nt) bbase[nt] = XKsrc + (nt * 16 + l15) * ROWB;

#define LD_A(ks, A) { _Pragma("unroll") for (int mt_ = 0; mt_ < 4; ++mt_) \
    A[mt_] = *(const bf16x8*)(Ag + (ks) * 8192 + mt_ * 1024); }
#define LD_B(ks, Bv) { const int csn_ = (ks) & (NCS - 1); \
    _Pragma("unroll") for (int nt_ = 0; nt_ < 4; ++nt_) \
    Bv[nt_] = *(const bf16x8*)(bbase[nt_] + ((((csn_ << 2) + kseg) ^ e7) << 4)); }
#define MM(A, Bv, FIRST) { _Pragma("unroll") for (int mt_ = 0; mt_ < 4; ++mt_) \
    _Pragma("unroll") for (int nt_ = 0; nt_ < 4; ++nt_) \
    accf[mt_][nt_] = __builtin_amdgcn_mfma_f32_16x16x32_bf16(A[mt_], Bv[nt_], \
        (FIRST) ? ZERO : accf[mt_][nt_], 0, 0, 0); }

    LD_A(0, a0); LD_B(0, b0);
    for (int fl = 0; fl < 16; ++fl) {
        const int fg = kg * 16 + fl;
        const int fsw = (((fg >> 3) ^ e7) << 4) | ((fg & 7) << 1);
        float x0v[4];
#pragma unroll
        for (int nt = 0; nt < 4; ++nt)
            x0v[nt] = b2f(*(const unsigned short*)(X0T + (nt * 16 + l15) * 128 + fsw));
        const int ks0 = fl * NCS;
#pragma unroll
        for (int cs = 0; cs < NCS; ++cs) {
            const int nks = ks0 + cs + 1;
            if (cs & 1) {
                if (cs < NCS - 1)      { LD_A(nks, a0); LD_B(nks, b0); }
                else if (fl < 15)      { LD_A(nks, a0); LD_B(nks, b0); }
                MM(a1, b1, cs == 0);
            } else {
                if (cs < NCS - 1)      { LD_A(nks, a1); LD_B(nks, b1); }
                else if (fl < 15)      { LD_A(nks, a1); LD_B(nks, b1); }
                MM(a0, b0, cs == 0);
            }
        }
        // fold x0[f,e] scale into the f32 running accumulator (col e = nt*16+l15)
#pragma unroll
        for (int nt = 0; nt < 4; ++nt) {
            const f32x4 xv = {x0v[nt], x0v[nt], x0v[nt], x0v[nt]};
#pragma unroll
            for (int mt = 0; mt < 4; ++mt)
                acc[mt][nt] += accf[mt][nt] * xv;
        }
    }
#undef LD_A
#undef LD_B
#undef MM

    // ---- cross-kg reduction ----
    if (kg != 0) {
        char* slot = RED + (mh * 3 + (kg - 1)) * 16384;
#pragma unroll
        for (int mt = 0; mt < 4; ++mt)
#pragma unroll
            for (int nt = 0; nt < 4; ++nt)
                *(f32x4*)(slot + ((mt * 4 + nt) * 64 + lane) * 16) = acc[mt][nt];
    }
    __syncthreads();
    if (kg == 0) {
#pragma unroll
        for (int s = 0; s < 3; ++s) {
            const char* slot = RED + (mh * 3 + s) * 16384;
#pragma unroll
            for (int mt = 0; mt < 4; ++mt)
#pragma unroll
                for (int nt = 0; nt < 4; ++nt)
                    acc[mt][nt] += *(const f32x4*)(slot + ((mt * 4 + nt) * 64 + lane) * 16);
        }
        const int r0 = (lane >> 4) * 4;
#pragma unroll
        for (int mt = 0; mt < 4; ++mt) {
            const int om = mh * 64 + mt * 16 + r0;
            const float4 wa = *(const float4*)(Wa_l + om);
            const int osw = (((om >> 3) ^ e7) << 4) | ((om & 7) << 1);
#pragma unroll
            for (int nt = 0; nt < 4; ++nt) {
                f32x4 v = acc[mt][nt];
                v.x = fmaxf(v.x, 0.f); v.y = fmaxf(v.y, 0.f);
                v.z = fmaxf(v.z, 0.f); v.w = fmaxf(v.w, 0.f);
                ypart = fmaf(wa.x, v.x, ypart);
                ypart = fmaf(wa.y, v.y, ypart);
                ypart = fmaf(wa.z, v.z, ypart);
                ypart = fmaf(wa.w, v.w, ypart);
                if (!LAST) {
                    unsigned lo = (unsigned)f2b(v.x) | ((unsigned)f2b(v.y) << 16);
                    unsigned hi = (unsigned)f2b(v.z) | ((unsigned)f2b(v.w) << 16);
                    *(uint2*)(XKdst + (nt * 16 + l15) * 256 + osw) = make_uint2(lo, hi);
                }
            }
        }
    }
    __syncthreads();
}

__global__ __launch_bounds__(512, 2) void cin_main(
    const unsigned short* __restrict__ Wp0,
    const unsigned short* __restrict__ Wp1,
    const unsigned short* __restrict__ Wp2,
    const unsigned short* __restrict__ x0t,
    const float* __restrict__ Wa,
    float* __restrict__ y)
{
    extern __shared__ char sm[];
    const int b = blockIdx.x, tid = threadIdx.x;
    const int lane = tid & 63, w = tid >> 6;
    const int mh = w & 1, kg = w >> 1;
    const int l15 = lane & 15, kseg = lane >> 4, e7 = lane & 7;

    // stage x0t (8 KB) via DMA: per-wave linear 1KB chunks
    async16((const char*)x0t + (size_t)b * 8192 + w * 1024 + lane * 16,
            sm + X0T_OFF + w * 1024);
    __syncthreads();

    float ypart = 0.f;
    const char* Ag0 = (const char*)Wp0 + (size_t)kg * 16 * 2 * 8192 + mh * 4096 + lane * 16;
    do_layer<2, 128, false>(Ag0, sm + X0T_OFF, sm + XKA_OFF, sm + X0T_OFF, sm + RED_OFF,
                            Wa + 0, ypart, lane, l15, kseg, e7, mh, kg);
    const char* Ag1 = (const char*)Wp1 + (size_t)kg * 16 * 4 * 8192 + mh * 4096 + lane * 16;
    do_layer<4, 256, false>(Ag1, sm + XKA_OFF, sm + XKB_OFF, sm + X0T_OFF, sm + RED_OFF,
                            Wa + 128, ypart, lane, l15, kseg, e7, mh, kg);
    const char* Ag2 = (const char*)Wp2 + (size_t)kg * 16 * 4 * 8192 + mh * 4096 + lane * 16;
    do_layer<4, 256, true>(Ag2, sm + XKB_OFF, sm + XKA_OFF, sm + X0T_OFF, sm + RED_OFF,
                           Wa + 256, ypart, lane, l15, kseg, e7, mh, kg);

#pragma unroll
    for (int off = 32; off >= 1; off >>= 1)
        ypart += __shfl_down(ypart, off, 64);
    float* YS = (float*)(sm + YS_OFF);
    if (lane == 0 && kg == 0) YS[mh] = ypart;
    __syncthreads();
    if (tid == 0) y[b] = YS[0] + YS[1];
}

extern "C" void kernel_launch(void* const* d_in, const int* in_sizes, int n_in,
                              void* d_out, int out_size, void* d_ws, size_t ws_size,
                              hipStream_t stream) {
    const float* x  = (const float*)d_in[0];
    const float* W0 = (const float*)d_in[1];
    const float* W1 = (const float*)d_in[2];
    const float* W2 = (const float*)d_in[3];
    const float* Wa = (const float*)d_in[4];
    float* y = (float*)d_out;

    char* ws = (char*)d_ws;
    unsigned short* Wp0 = (unsigned short*)(ws);               // 1 MB
    unsigned short* Wp1 = (unsigned short*)(ws + (1u << 20));  // 2 MB
    unsigned short* Wp2 = (unsigned short*)(ws + (3u << 20));  // 2 MB
    unsigned short* x0t = (unsigned short*)(ws + (5u << 20));  // 2 MB

    hipLaunchKernelGGL(prep_w, dim3(2048), dim3(256), 0, stream, W0, Wp0, 6, 12);
    hipLaunchKernelGGL(prep_w, dim3(4096), dim3(256), 0, stream, W1, Wp1, 7, 13);
    hipLaunchKernelGGL(prep_w, dim3(4096), dim3(256), 0, stream, W2, Wp2, 7, 13);
    hipLaunchKernelGGL(prep_x, dim3(4096), dim3(256), 0, stream, x, x0t);

    hipFuncSetAttribute((const void*)cin_main, hipFuncAttributeMaxDynamicSharedMemorySize, SMEM_SZ);
    hipLaunchKernelGGL(cin_main, dim3(NBATCH), dim3(512), SMEM_SZ, stream,
                       Wp0, Wp1, Wp2, x0t, Wa, y);
}

// Round 4
// 102.179 us; speedup vs baseline: 15.6574x; 1.0458x over previous
//
#include <hip/hip_runtime.h>

#define NBATCH 256
#define NFILT  128

typedef __attribute__((ext_vector_type(8))) short bf16x8;
typedef __attribute__((ext_vector_type(4))) float f32x4;

__device__ __forceinline__ unsigned short f2b(float f) {
    unsigned u = __float_as_uint(f);
    u = (u + 0x7fffu + ((u >> 16) & 1u)) >> 16;
    return (unsigned short)u;
}
__device__ __forceinline__ float b2f(unsigned short h) {
    return __uint_as_float(((unsigned)h) << 16);
}
__device__ __forceinline__ void async16(const void* g, void* l) {
    __builtin_amdgcn_global_load_lds((const __attribute__((address_space(1))) unsigned int*)g,
                                     (__attribute__((address_space(3))) unsigned int*)l, 16, 0, 0);
}

// ---- LDS map ----
#define XKA_OFF 0        // 16 KB  xk layer0->1  [e][c] swizzled, ROWB 256
#define XKB_OFF 16384    // 16 KB  xk layer1->2
#define X0T_OFF 32768    // 8 KB   x0 transposed [e][c=f] swizzled, ROWB 128 (layer-0 B src)
#define X0F_OFF 40960    // 8 KB   x0 [f][e] linear (fold reads, conflict-free)
#define RED_OFF 49152    // 96 KB  6 slots x 16KB cross-kg reduction
#define YS_OFF  147456
#define SMEM_SZ 147520

// ---------------- fused prep kernel ----------------
// blocks [0,2048): W0 ; [2048,6144): W1 ; [6144,10240): W2 ; [10240,14336): x
__global__ void prep_all(const float* __restrict__ x,
                         const float* __restrict__ W0,
                         const float* __restrict__ W1,
                         const float* __restrict__ W2,
                         unsigned short* __restrict__ x0t,
                         unsigned short* __restrict__ x0f,
                         unsigned short* __restrict__ Wp0,
                         unsigned short* __restrict__ Wp1,
                         unsigned short* __restrict__ Wp2)
{
    const int bid = blockIdx.x, tid = threadIdx.x;
    if (bid < 10240) {
        const float* W; unsigned short* Wp; int CLOG, KLOG, idx;
        if (bid < 2048)      { W = W0; Wp = Wp0; CLOG = 6; KLOG = 12; idx = bid * 256 + tid; }
        else if (bid < 6144) { W = W1; Wp = Wp1; CLOG = 7; KLOG = 13; idx = (bid - 2048) * 256 + tid; }
        else                 { W = W2; Wp = Wp2; CLOG = 7; KLOG = 13; idx = (bid - 6144) * 256 + tid; }
        int o = idx >> KLOG, k = idx & ((1 << KLOG) - 1);
        int f = k >> CLOG, c = k & ((1 << CLOG) - 1);
        int kg = f >> 4, fl = f & 15;
        int cs = c >> 5, kseg = (c >> 3) & 3, j = c & 7;
        int mh = o >> 6, mt = (o >> 4) & 3, l15 = o & 15;
        int ncs = 1 << (CLOG - 5);
        size_t dst = ((((size_t)((kg * 16 + fl) * ncs + cs) * 2 + mh) * 4 + mt) * 64
                      + kseg * 16 + l15) * 8 + j;
        Wp[dst] = f2b(W[idx]);
    } else {
        int idx = (bid - 10240) * 256 + tid;
        int b = idx >> 12, r = idx & 4095, f = r >> 6, e = r & 63;
        unsigned short v = f2b(x[idx]);
        x0f[b * 4096 + f * 64 + e] = v;
        x0t[b * 4096 + e * 64 + ((((f >> 3) ^ (e & 7)) << 3) | (f & 7))] = v;
    }
}

// ---------------- main kernel ----------------
template<int NCS, int ROWB, bool LAST>
__device__ __forceinline__ void do_layer(
    const char* __restrict__ Ag,       // per-wave A stream base (global, pre-tiled bf16)
    const char* __restrict__ XKsrc,    // LDS B source [e][c] swizzled
    char* __restrict__ XKdst,          // LDS xk-next (ROWB 256)
    const char* __restrict__ X0F,      // LDS x0 [f][e] (fold scales)
    char* __restrict__ RED,
    const float* __restrict__ Wa_l,
    float& ypart, int lane, int l15, int kseg, int e7, int mh, int kg)
{
    const f32x4 ZERO = {0.f, 0.f, 0.f, 0.f};
    f32x4 acc[4][4];
#pragma unroll
    for (int mt = 0; mt < 4; ++mt)
#pragma unroll
        for (int nt = 0; nt < 4; ++nt) acc[mt][nt] = ZERO;

    // B operand is field-invariant: load the wave's NCS x 4 granules ONCE per layer.
    bf16x8 bq[NCS][4];
#pragma unroll
    for (int cs = 0; cs < NCS; ++cs)
#pragma unroll
        for (int nt = 0; nt < 4; ++nt)
            bq[cs][nt] = *(const bf16x8*)(XKsrc + (nt * 16 + l15) * ROWB
                                          + ((((cs << 2) + kseg) ^ e7) << 4));

    // A queue: 2 slots, 1 k-step ahead, static slot indices.
    bf16x8 aq[2][4];
#pragma unroll
    for (int mt = 0; mt < 4; ++mt)
        aq[0][mt] = *(const bf16x8*)(Ag + mt * 1024);

    f32x4 accf[4][4];
    for (int fl = 0; fl < 16; ++fl) {
        const unsigned short* xf = (const unsigned short*)(X0F + ((kg * 16 + fl) << 7));
        const float x0v0 = b2f(xf[l15]);
        const float x0v1 = b2f(xf[16 + l15]);
        const float x0v2 = b2f(xf[32 + l15]);
        const float x0v3 = b2f(xf[48 + l15]);
        const size_t ksf = (size_t)fl * NCS;
#pragma unroll
        for (int cs = 0; cs < NCS; ++cs) {
            // prefetch A for k-step ks+1 (overshoot at layer end is harmless)
#pragma unroll
            for (int mt = 0; mt < 4; ++mt)
                aq[(cs + 1) & 1][mt] =
                    *(const bf16x8*)(Ag + (ksf + cs + 1) * 8192 + mt * 1024);
#pragma unroll
            for (int mt = 0; mt < 4; ++mt)
#pragma unroll
                for (int nt = 0; nt < 4; ++nt)
                    accf[mt][nt] = __builtin_amdgcn_mfma_f32_16x16x32_bf16(
                        aq[cs & 1][mt], bq[cs][nt],
                        (cs == 0) ? ZERO : accf[mt][nt], 0, 0, 0);
        }
        // fold x0[f,e] into the running f32 accumulator
#pragma unroll
        for (int mt = 0; mt < 4; ++mt) {
            acc[mt][0] += accf[mt][0] * x0v0;
            acc[mt][1] += accf[mt][1] * x0v1;
            acc[mt][2] += accf[mt][2] * x0v2;
            acc[mt][3] += accf[mt][3] * x0v3;
        }
    }

    // ---- cross-kg reduction ----
    if (kg != 0) {
        char* slot = RED + (mh * 3 + (kg - 1)) * 16384;
#pragma unroll
        for (int mt = 0; mt < 4; ++mt)
#pragma unroll
            for (int nt = 0; nt < 4; ++nt)
                *(f32x4*)(slot + ((mt * 4 + nt) * 64 + lane) * 16) = acc[mt][nt];
    }
    __syncthreads();
    if (kg == 0) {
#pragma unroll
        for (int s = 0; s < 3; ++s) {
            const char* slot = RED + (mh * 3 + s) * 16384;
#pragma unroll
            for (int mt = 0; mt < 4; ++mt)
#pragma unroll
                for (int nt = 0; nt < 4; ++nt)
                    acc[mt][nt] += *(const f32x4*)(slot + ((mt * 4 + nt) * 64 + lane) * 16);
        }
        const int r0 = (lane >> 4) * 4;
#pragma unroll
        for (int mt = 0; mt < 4; ++mt) {
            const int om = mh * 64 + mt * 16 + r0;
            const float4 wa = *(const float4*)(Wa_l + om);
            const int osw = (((om >> 3) ^ e7) << 4) | ((om & 7) << 1);
#pragma unroll
            for (int nt = 0; nt < 4; ++nt) {
                f32x4 v = acc[mt][nt];
                v.x = fmaxf(v.x, 0.f); v.y = fmaxf(v.y, 0.f);
                v.z = fmaxf(v.z, 0.f); v.w = fmaxf(v.w, 0.f);
                ypart = fmaf(wa.x, v.x, ypart);
                ypart = fmaf(wa.y, v.y, ypart);
                ypart = fmaf(wa.z, v.z, ypart);
                ypart = fmaf(wa.w, v.w, ypart);
                if (!LAST) {
                    unsigned lo = (unsigned)f2b(v.x) | ((unsigned)f2b(v.y) << 16);
                    unsigned hi = (unsigned)f2b(v.z) | ((unsigned)f2b(v.w) << 16);
                    *(uint2*)(XKdst + (nt * 16 + l15) * 256 + osw) = make_uint2(lo, hi);
                }
            }
        }
    }
    __syncthreads();
}

__global__ __launch_bounds__(512, 2) void cin_main(
    const unsigned short* __restrict__ Wp0,
    const unsigned short* __restrict__ Wp1,
    const unsigned short* __restrict__ Wp2,
    const unsigned short* __restrict__ x0t,
    const unsigned short* __restrict__ x0f,
    const float* __restrict__ Wa,
    float* __restrict__ y)
{
    extern __shared__ char sm[];
    const int b = blockIdx.x, tid = threadIdx.x;
    const int lane = tid & 63, w = tid >> 6;
    const int mh = w & 1, kg = w >> 1;
    const int l15 = lane & 15, kseg = lane >> 4, e7 = lane & 7;

    // stage x0t + x0f (8 KB each) via DMA: per-wave linear 1KB chunks
    async16((const char*)x0t + (size_t)b * 8192 + w * 1024 + lane * 16,
            sm + X0T_OFF + w * 1024);
    async16((const char*)x0f + (size_t)b * 8192 + w * 1024 + lane * 16,
            sm + X0F_OFF + w * 1024);
    __syncthreads();

    float ypart = 0.f;
    const char* Ag0 = (const char*)Wp0 + (size_t)kg * 16 * 2 * 8192 + mh * 4096 + lane * 16;
    do_layer<2, 128, false>(Ag0, sm + X0T_OFF, sm + XKA_OFF, sm + X0F_OFF, sm + RED_OFF,
                            Wa + 0, ypart, lane, l15, kseg, e7, mh, kg);
    const char* Ag1 = (const char*)Wp1 + (size_t)kg * 16 * 4 * 8192 + mh * 4096 + lane * 16;
    do_layer<4, 256, false>(Ag1, sm + XKA_OFF, sm + XKB_OFF, sm + X0F_OFF, sm + RED_OFF,
                            Wa + 128, ypart, lane, l15, kseg, e7, mh, kg);
    const char* Ag2 = (const char*)Wp2 + (size_t)kg * 16 * 4 * 8192 + mh * 4096 + lane * 16;
    do_layer<4, 256, true>(Ag2, sm + XKB_OFF, sm + XKA_OFF, sm + X0F_OFF, sm + RED_OFF,
                           Wa + 256, ypart, lane, l15, kseg, e7, mh, kg);

#pragma unroll
    for (int off = 32; off >= 1; off >>= 1)
        ypart += __shfl_down(ypart, off, 64);
    float* YS = (float*)(sm + YS_OFF);
    if (lane == 0 && kg == 0) YS[mh] = ypart;
    __syncthreads();
    if (tid == 0) y[b] = YS[0] + YS[1];
}

extern "C" void kernel_launch(void* const* d_in, const int* in_sizes, int n_in,
                              void* d_out, int out_size, void* d_ws, size_t ws_size,
                              hipStream_t stream) {
    const float* x  = (const float*)d_in[0];
    const float* W0 = (const float*)d_in[1];
    const float* W1 = (const float*)d_in[2];
    const float* W2 = (const float*)d_in[3];
    const float* Wa = (const float*)d_in[4];
    float* y = (float*)d_out;

    char* ws = (char*)d_ws;
    unsigned short* Wp0 = (unsigned short*)(ws);               // 1 MB
    unsigned short* Wp1 = (unsigned short*)(ws + (1u << 20));  // 2 MB
    unsigned short* Wp2 = (unsigned short*)(ws + (3u << 20));  // 2 MB
    unsigned short* x0t = (unsigned short*)(ws + (5u << 20));  // 2 MB
    unsigned short* x0f = (unsigned short*)(ws + (7u << 20));  // 2 MB

    hipLaunchKernelGGL(prep_all, dim3(14336), dim3(256), 0, stream,
                       x, W0, W1, W2, x0t, x0f, Wp0, Wp1, Wp2);

    hipFuncSetAttribute((const void*)cin_main, hipFuncAttributeMaxDynamicSharedMemorySize, SMEM_SZ);
    hipLaunchKernelGGL(cin_main, dim3(NBATCH), dim3(512), SMEM_SZ, stream,
                       Wp0, Wp1, Wp2, x0t, x0f, Wa, y);
}